// Round 8
// baseline (87.936 us; speedup 1.0000x reference)
//
#include <hip/hip_runtime.h>
#include <hip/hip_bf16.h>
#include <stdint.h>

// PatchExpanding: LN(384) -> Linear 384->1536 -> 2x2x2 pixel shuffle (6/8 parities live)
// x: (2,16,32,32,384) f32; W: (384,1536) f32; out: (2,32,64,64,192) f32
// position p in [0,32768): w=p&31, h=(p>>5)&31, d=(p>>10)&15, b=p>>14
//
// ws layout: xn bf16 [32768][384] at +0 ; Wt bf16 [1152][384] at +25165824
// Round 8 = round 5 (best, 71.5us) with dead-parity zeroing moved from the
//           BW-saturated lnwt into the BW-idle gemm (nt==0 blocks).
// Fallback (ws too small): round-1 scheme staging in d_out's dead parity regions.

typedef __attribute__((ext_vector_type(4))) float f32x4;
typedef __attribute__((ext_vector_type(8))) short s16x8;
typedef __attribute__((ext_vector_type(4))) unsigned short u16x4;
typedef const __attribute__((address_space(1))) void gvoid_t;
typedef __attribute__((address_space(3))) void lvoid_t;

__device__ __forceinline__ int ob_of_p(int p) {
    // base offset (floats) of output cell (b, 2d, 2h, 2w, 0)
    const int w = p & 31, h = (p >> 5) & 31, d = (p >> 10) & 15, b = p >> 14;
    return b * 25165824 + d * 1572864 + h * 24576 + w * 384;
}

__device__ __forceinline__ unsigned short f2bf(float f) {
    unsigned u = __builtin_bit_cast(unsigned, f);
    u += 0x7fffu + ((u >> 16) & 1u);   // RNE, no NaN in this data
    return (unsigned short)(u >> 16);
}

// ============================ PRIMARY (ws) PATH ==============================

// kernel 1: blocks [0,8192): LayerNorm -> xn bf16
//           blocks [8192,9920): W -> Wt bf16 [1152][384], cols {0,1,4,5,6,7}
__global__ __launch_bounds__(256) void lnwt_kernel(const float* __restrict__ x,
                                                   const float* __restrict__ gamma,
                                                   const float* __restrict__ beta,
                                                   const float* __restrict__ W,
                                                   unsigned short* __restrict__ xn,
                                                   unsigned short* __restrict__ wt) {
    if (blockIdx.x >= 8192) {
        const int t = (blockIdx.x - 8192) * 256 + threadIdx.x;  // < 442368
        const int k = t % 384;
        const int n = t / 384;
        const int s = n / 192;                                   // slot 0..5
        const int oc = (s < 2 ? s : s + 2) * 192 + (n % 192);
        wt[(size_t)n * 384 + k] = f2bf(W[(size_t)k * 1536 + oc]);
        return;
    }
    const int wv = threadIdx.x >> 6;
    const int l  = threadIdx.x & 63;
    const int p  = blockIdx.x * 4 + wv;
    const float* row = x + (size_t)p * 384;
    f32x4 v0 = *(const f32x4*)(row + l * 4);              // ch 0..255
    f32x4 v1 = {0.f, 0.f, 0.f, 0.f};
    if (l < 32) v1 = *(const f32x4*)(row + 256 + l * 4);  // ch 256..383
    float s  = v0[0]+v0[1]+v0[2]+v0[3] + v1[0]+v1[1]+v1[2]+v1[3];
    float s2 = v0[0]*v0[0]+v0[1]*v0[1]+v0[2]*v0[2]+v0[3]*v0[3]
             + v1[0]*v1[0]+v1[1]*v1[1]+v1[2]*v1[2]+v1[3]*v1[3];
    #pragma unroll
    for (int off = 32; off >= 1; off >>= 1) {
        s  += __shfl_xor(s,  off);
        s2 += __shfl_xor(s2, off);
    }
    const float mu = s * (1.f / 384.f);
    const float rs = rsqrtf(s2 * (1.f / 384.f) - mu * mu + 1e-5f);
    unsigned short* dst = xn + (size_t)p * 384;
    f32x4 g0 = *(const f32x4*)(gamma + l * 4);
    f32x4 b0 = *(const f32x4*)(beta  + l * 4);
    u16x4 o0;
    #pragma unroll
    for (int j = 0; j < 4; ++j) o0[j] = f2bf((v0[j] - mu) * rs * g0[j] + b0[j]);
    *(u16x4*)(dst + l * 4) = o0;
    if (l < 32) {
        f32x4 g1 = *(const f32x4*)(gamma + 256 + l * 4);
        f32x4 b1 = *(const f32x4*)(beta  + 256 + l * 4);
        u16x4 o1;
        #pragma unroll
        for (int j = 0; j < 4; ++j) o1[j] = f2bf((v1[j] - mu) * rs * g1[j] + b1[j]);
        *(u16x4*)(dst + 256 + l * 4) = o1;
    }
}

// kernel 2: MFMA GEMM + scatter epilogue. 2-phase dbuf, NT output stores.
// 128x128 tile, BK=64, 256 thr (4 waves 2x2). A+B staged via global_load_lds
// into 32 KB buffers, double-buffered (64 KB). STAGE(t+1) issued before
// compute(t); one __syncthreads per K-step. nt==0 blocks also zero the two
// dead parity regions for their 128 positions (overlaps idle write BW).
__global__ __launch_bounds__(256) void gemm3_kernel(const unsigned short* __restrict__ xn,
                                                    const unsigned short* __restrict__ wt,
                                                    float* __restrict__ outf) {
    __shared__ char lds[65536];   // buf k at k*32768: A [0,16K), B [16K,32K)
    const char* xb = (const char*)xn;
    const char* wb = (const char*)wt;
    const int tid = threadIdx.x;
    const int wv = tid >> 6, l = tid & 63;
    int bid = blockIdx.x;
    bid = (bid & 7) * 288 + (bid >> 3);  // XCD swizzle (2304 = 8*288, bijective)
    const int mt = bid / 9, nt = bid % 9;
    const int m0 = mt * 128, n0 = nt * 128;
    const int wm = wv >> 1, wn = wv & 1;

    // staging: inst i covers rows wv*32+i*8..+8; lane l -> row +(l>>3), chunk l&7
    // LDS dest linear; global source pre-swizzled (chunk ^ row&7)
    size_t srcA[4], srcB[4];
    int ldsA[4], ldsB[4];
    #pragma unroll
    for (int i = 0; i < 4; ++i) {
        const int r = wv * 32 + i * 8 + (l >> 3);
        const int swz = ((l & 7) * 16) ^ ((r & 7) << 4);
        srcA[i] = (size_t)(m0 + r) * 768 + swz;
        srcB[i] = (size_t)(n0 + r) * 768 + swz;
        ldsA[i] = (wv * 32 + i * 8) * 128;
        ldsB[i] = 16384 + (wv * 32 + i * 8) * 128;
    }

    // prologue: stage K-tile 0 into buf 0 (issue before the zero-writes)
    #pragma unroll
    for (int i = 0; i < 4; ++i) {
        __builtin_amdgcn_global_load_lds((gvoid_t*)(xb + srcA[i]),
                                         (lvoid_t*)(lds + ldsA[i]), 16, 0, 0);
        __builtin_amdgcn_global_load_lds((gvoid_t*)(wb + srcB[i]),
                                         (lvoid_t*)(lds + ldsB[i]), 16, 0, 0);
    }

    // dead-parity zeros: (0,1,1)@+12480, (1,1,0)@+798720, 48 floats per position
    if (nt == 0) {
        const int p  = m0 + (tid >> 1);
        const int ob = ob_of_p(p) + ((tid & 1) ? 798720 : 12480);
        const f32x4 z = {0.f, 0.f, 0.f, 0.f};
        #pragma unroll
        for (int j = 0; j < 12; ++j)
            __builtin_nontemporal_store(z, (f32x4*)(outf + ob + j * 4));
    }

    f32x4 acc[4][4];
    const f32x4 fz = {0.f, 0.f, 0.f, 0.f};
    #pragma unroll
    for (int m = 0; m < 4; ++m)
        #pragma unroll
        for (int n = 0; n < 4; ++n) acc[m][n] = fz;

    int arow[4], brow[4];
    #pragma unroll
    for (int i = 0; i < 4; ++i) {
        arow[i] = wm * 64 + i * 16 + (l & 15);
        brow[i] = wn * 64 + i * 16 + (l & 15);
    }
    const int kbyte0 = (l >> 4) * 16;
    __syncthreads();

    #pragma unroll
    for (int t = 0; t < 6; ++t) {        // K = 384 = 6 * 64
        const int cur = (t & 1) * 32768;
        const int nxt = 32768 - cur;
        if (t < 5) {                     // prefetch next K-tile (in flight during MFMA)
            #pragma unroll
            for (int i = 0; i < 4; ++i) {
                __builtin_amdgcn_global_load_lds((gvoid_t*)(xb + srcA[i] + (t + 1) * 128),
                                                 (lvoid_t*)(lds + nxt + ldsA[i]), 16, 0, 0);
                __builtin_amdgcn_global_load_lds((gvoid_t*)(wb + srcB[i] + (t + 1) * 128),
                                                 (lvoid_t*)(lds + nxt + ldsB[i]), 16, 0, 0);
            }
        }
        #pragma unroll
        for (int kk = 0; kk < 2; ++kk) {
            const int kbyte = kbyte0 + kk * 64;
            s16x8 a[4], b[4];
            #pragma unroll
            for (int m = 0; m < 4; ++m)
                a[m] = *(const s16x8*)(lds + cur + arow[m] * 128 + (kbyte ^ ((arow[m] & 7) << 4)));
            #pragma unroll
            for (int n = 0; n < 4; ++n)
                b[n] = *(const s16x8*)(lds + cur + 16384 + brow[n] * 128 + (kbyte ^ ((brow[n] & 7) << 4)));
            #pragma unroll
            for (int m = 0; m < 4; ++m)
                #pragma unroll
                for (int n = 0; n < 4; ++n)
                    acc[m][n] = __builtin_amdgcn_mfma_f32_16x16x32_bf16(a[m], b[n], acc[m][n], 0, 0, 0);
        }
        __syncthreads();                 // stage(t+1) drained + cur free for reuse
    }

    // epilogue: D row = (l>>4)*4 + reg, col = l&15 (per 16x16 fragment); NT stores
    int coladd[4];
    #pragma unroll
    for (int n = 0; n < 4; ++n) {
        const int gnb = n0 + wn * 64 + n * 16;   // 16-col group never crosses a slot
        const int s = gnb / 192;
        int d;
        if      (s == 0) d = 0;        // ch0 -> (0,0,0)
        else if (s == 1) d = 786432;   // ch1 -> (1,0,0)
        else if (s == 2) d = 786624;   // ch4 -> (1,0,1)
        else if (s == 3) d = 12288;    // ch5 -> (0,1,0)
        else if (s == 4) d = 192;      // ch6 -> (0,0,1)
        else             d = 798912;   // ch7 -> (1,1,1)
        coladd[n] = d + (gnb % 192) + (l & 15);
    }
    const int pb = m0 + wm * 64 + (l >> 4) * 4;
    #pragma unroll
    for (int m = 0; m < 4; ++m) {
        #pragma unroll
        for (int r = 0; r < 4; ++r) {
            const int ob = ob_of_p(pb + m * 16 + r);
            #pragma unroll
            for (int n = 0; n < 4; ++n)
                __builtin_nontemporal_store(acc[m][n][r], outf + ob + coladd[n]);
        }
    }
}

// ============================ FALLBACK (round-1) PATH ========================

__global__ __launch_bounds__(256) void ln_kernel(const float* __restrict__ x,
                                                 const float* __restrict__ gamma,
                                                 const float* __restrict__ beta,
                                                 float* __restrict__ outf) {
    const int wv = threadIdx.x >> 6;
    const int l  = threadIdx.x & 63;
    const int p  = blockIdx.x * 4 + wv;
    const float* row = x + (size_t)p * 384;
    f32x4 v0 = *(const f32x4*)(row + l * 4);
    f32x4 v1 = {0.f, 0.f, 0.f, 0.f};
    if (l < 32) v1 = *(const f32x4*)(row + 256 + l * 4);
    float s  = v0[0]+v0[1]+v0[2]+v0[3] + v1[0]+v1[1]+v1[2]+v1[3];
    float s2 = v0[0]*v0[0]+v0[1]*v0[1]+v0[2]*v0[2]+v0[3]*v0[3]
             + v1[0]*v1[0]+v1[1]*v1[1]+v1[2]*v1[2]+v1[3]*v1[3];
    #pragma unroll
    for (int off = 32; off >= 1; off >>= 1) {
        s  += __shfl_xor(s,  off);
        s2 += __shfl_xor(s2, off);
    }
    const float mu = s * (1.f / 384.f);
    const float rs = rsqrtf(s2 * (1.f / 384.f) - mu * mu + 1e-5f);
    unsigned short* dst = (unsigned short*)(outf + ob_of_p(p) + 12480);
    f32x4 g0 = *(const f32x4*)(gamma + l * 4);
    f32x4 b0 = *(const f32x4*)(beta  + l * 4);
    u16x4 o0;
    #pragma unroll
    for (int j = 0; j < 4; ++j) o0[j] = f2bf((v0[j] - mu) * rs * g0[j] + b0[j]);
    *(u16x4*)(dst + l * 4) = o0;
    if (l < 32) {
        f32x4 g1 = *(const f32x4*)(gamma + 256 + l * 4);
        f32x4 b1 = *(const f32x4*)(beta  + 256 + l * 4);
        u16x4 o1;
        #pragma unroll
        for (int j = 0; j < 4; ++j) o1[j] = f2bf((v1[j] - mu) * rs * g1[j] + b1[j]);
        *(u16x4*)(dst + 256 + l * 4) = o1;
    }
}

__global__ __launch_bounds__(256) void wt_kernel(const float* __restrict__ W,
                                                 float* __restrict__ outf) {
    const int t = blockIdx.x * 256 + threadIdx.x;
    const int k = t % 384;
    const int n = t / 384;
    const int s = n / 192;
    const int oc = (s < 2 ? s : s + 2) * 192 + (n % 192);
    const float v = W[(size_t)k * 1536 + oc];
    unsigned short* dst = (unsigned short*)(outf + ob_of_p(n) + 798720);
    dst[k] = f2bf(v);
}

__global__ __launch_bounds__(256) void gemm_kernel(float* __restrict__ outf) {
    __shared__ char lds[32768];
    const char* gbase = (const char*)outf;
    const int tid = threadIdx.x;
    const int wv = tid >> 6, l = tid & 63;
    int bid = blockIdx.x;
    bid = (bid & 7) * 288 + (bid >> 3);
    const int mt = bid / 9, nt = bid % 9;
    const int m0 = mt * 128, n0 = nt * 128;
    size_t srcA[4], srcB[4];
    int ldsA[4], ldsB[4];
    #pragma unroll
    for (int i = 0; i < 4; ++i) {
        const int r = wv * 32 + i * 8 + (l >> 3);
        const int swz = ((l & 7) * 16) ^ ((r & 7) << 4);
        srcA[i] = (size_t)(ob_of_p(m0 + r) + 12480)  * 4 + swz;
        srcB[i] = (size_t)(ob_of_p(n0 + r) + 798720) * 4 + swz;
        ldsA[i] = (wv * 32 + i * 8) * 128;
        ldsB[i] = 16384 + (wv * 32 + i * 8) * 128;
    }
    f32x4 acc[4][4];
    const f32x4 fz = {0.f, 0.f, 0.f, 0.f};
    #pragma unroll
    for (int m = 0; m < 4; ++m)
        #pragma unroll
        for (int n = 0; n < 4; ++n) acc[m][n] = fz;
    const int wm = wv >> 1, wn = wv & 1;
    int arow[4], brow[4];
    #pragma unroll
    for (int i = 0; i < 4; ++i) {
        arow[i] = wm * 64 + i * 16 + (l & 15);
        brow[i] = wn * 64 + i * 16 + (l & 15);
    }
    const int kbyte0 = (l >> 4) * 16;
    for (int t = 0; t < 6; ++t) {
        const int kb = t * 128;
        #pragma unroll
        for (int i = 0; i < 4; ++i)
            __builtin_amdgcn_global_load_lds((gvoid_t*)(gbase + srcA[i] + kb),
                                             (lvoid_t*)(lds + ldsA[i]), 16, 0, 0);
        #pragma unroll
        for (int i = 0; i < 4; ++i)
            __builtin_amdgcn_global_load_lds((gvoid_t*)(gbase + srcB[i] + kb),
                                             (lvoid_t*)(lds + ldsB[i]), 16, 0, 0);
        __syncthreads();
        #pragma unroll
        for (int kk = 0; kk < 2; ++kk) {
            const int kbyte = kbyte0 + kk * 64;
            s16x8 a[4], b[4];
            #pragma unroll
            for (int m = 0; m < 4; ++m)
                a[m] = *(const s16x8*)(lds + arow[m] * 128 + (kbyte ^ ((arow[m] & 7) << 4)));
            #pragma unroll
            for (int n = 0; n < 4; ++n)
                b[n] = *(const s16x8*)(lds + 16384 + brow[n] * 128 + (kbyte ^ ((brow[n] & 7) << 4)));
            #pragma unroll
            for (int m = 0; m < 4; ++m)
                #pragma unroll
                for (int n = 0; n < 4; ++n)
                    acc[m][n] = __builtin_amdgcn_mfma_f32_16x16x32_bf16(a[m], b[n], acc[m][n], 0, 0, 0);
        }
        __syncthreads();
    }
    int coladd[4];
    #pragma unroll
    for (int n = 0; n < 4; ++n) {
        const int gnb = n0 + wn * 64 + n * 16;
        const int s = gnb / 192;
        int d;
        if      (s == 0) d = 0;
        else if (s == 1) d = 786432;
        else if (s == 2) d = 786624;
        else if (s == 3) d = 12288;
        else if (s == 4) d = 192;
        else             d = 798912;
        coladd[n] = d + (gnb % 192) + (l & 15);
    }
    const int pb = m0 + wm * 64 + (l >> 4) * 4;
    #pragma unroll
    for (int m = 0; m < 4; ++m) {
        #pragma unroll
        for (int r = 0; r < 4; ++r) {
            const int ob = ob_of_p(pb + m * 16 + r);
            #pragma unroll
            for (int n = 0; n < 4; ++n)
                outf[ob + coladd[n]] = acc[m][n][r];
        }
    }
}

__global__ __launch_bounds__(256) void zero_kernel(float* __restrict__ outf) {
    const int idx = blockIdx.x * 256 + threadIdx.x;
    const int f4 = idx % 48;
    const int pr = (idx / 48) & 1;
    const int p  = idx / 96;
    const f32x4 z = {0.f, 0.f, 0.f, 0.f};
    *(f32x4*)(outf + ob_of_p(p) + (pr ? 798720 : 12480) + f4 * 4) = z;
}

// =============================================================================

extern "C" void kernel_launch(void* const* d_in, const int* in_sizes, int n_in,
                              void* d_out, int out_size, void* d_ws, size_t ws_size,
                              hipStream_t stream) {
    const float* x     = (const float*)d_in[0];
    const float* W     = (const float*)d_in[1];
    const float* gamma = (const float*)d_in[2];
    const float* beta  = (const float*)d_in[3];
    float* out = (float*)d_out;
    const size_t need = 25165824 + 884736;   // xn + Wt bf16
    if (ws_size >= need) {
        unsigned short* xn = (unsigned short*)d_ws;
        unsigned short* wt = (unsigned short*)((char*)d_ws + 25165824);
        lnwt_kernel <<<9920, 256, 0, stream>>>(x, gamma, beta, W, xn, wt);
        gemm3_kernel<<<2304, 256, 0, stream>>>(xn, wt, out);
    } else {
        ln_kernel  <<<8192,  256, 0, stream>>>(x, gamma, beta, out);
        wt_kernel  <<<1728,  256, 0, stream>>>(W, out);
        gemm_kernel<<<2304,  256, 0, stream>>>(out);
        zero_kernel<<<12288, 256, 0, stream>>>(out);
    }
}

// Round 9
// 69.190 us; speedup vs baseline: 1.2709x; 1.2709x over previous
//
#include <hip/hip_runtime.h>
#include <hip/hip_bf16.h>
#include <stdint.h>

// PatchExpanding: LN(384) -> Linear 384->1536 -> 2x2x2 pixel shuffle (6/8 parities live)
// x: (2,16,32,32,384) f32; W: (384,1536) f32; out: (2,32,64,64,192) f32
// position p in [0,32768): w=p&31, h=(p>>5)&31, d=(p>>10)&15, b=p>>14
//
// ws layout: xn bf16 [32768][384] at +0 ; Wt bf16 [1152][384] at +25165824
// Round 9 = round 5 (best, 71.5us) with the gemm's per-K-step full vmcnt(0)
//           drain replaced by counted vmcnt(8) + raw barriers (T4): tile t+1's
//           global_load_lds stay in flight across the barrier.
// Fallback (ws too small): round-1 scheme staging in d_out's dead parity regions.

typedef __attribute__((ext_vector_type(4))) float f32x4;
typedef __attribute__((ext_vector_type(8))) short s16x8;
typedef __attribute__((ext_vector_type(4))) unsigned short u16x4;
typedef const __attribute__((address_space(1))) void gvoid_t;
typedef __attribute__((address_space(3))) void lvoid_t;

__device__ __forceinline__ int ob_of_p(int p) {
    // base offset (floats) of output cell (b, 2d, 2h, 2w, 0)
    const int w = p & 31, h = (p >> 5) & 31, d = (p >> 10) & 15, b = p >> 14;
    return b * 25165824 + d * 1572864 + h * 24576 + w * 384;
}

__device__ __forceinline__ unsigned short f2bf(float f) {
    unsigned u = __builtin_bit_cast(unsigned, f);
    u += 0x7fffu + ((u >> 16) & 1u);   // RNE, no NaN in this data
    return (unsigned short)(u >> 16);
}

// ============================ PRIMARY (ws) PATH ==============================

// kernel 1: blocks [0,8192): LayerNorm -> xn bf16 + zero dead parities in out
//           blocks [8192,9920): W -> Wt bf16 [1152][384], cols {0,1,4,5,6,7}
__global__ __launch_bounds__(256) void lnwt_kernel(const float* __restrict__ x,
                                                   const float* __restrict__ gamma,
                                                   const float* __restrict__ beta,
                                                   const float* __restrict__ W,
                                                   float* __restrict__ outf,
                                                   unsigned short* __restrict__ xn,
                                                   unsigned short* __restrict__ wt) {
    if (blockIdx.x >= 8192) {
        const int t = (blockIdx.x - 8192) * 256 + threadIdx.x;  // < 442368
        const int k = t % 384;
        const int n = t / 384;
        const int s = n / 192;                                   // slot 0..5
        const int oc = (s < 2 ? s : s + 2) * 192 + (n % 192);
        wt[(size_t)n * 384 + k] = f2bf(W[(size_t)k * 1536 + oc]);
        return;
    }
    const int wv = threadIdx.x >> 6;
    const int l  = threadIdx.x & 63;
    const int p  = blockIdx.x * 4 + wv;
    const float* row = x + (size_t)p * 384;
    f32x4 v0 = *(const f32x4*)(row + l * 4);              // ch 0..255
    f32x4 v1 = {0.f, 0.f, 0.f, 0.f};
    if (l < 32) v1 = *(const f32x4*)(row + 256 + l * 4);  // ch 256..383
    float s  = v0[0]+v0[1]+v0[2]+v0[3] + v1[0]+v1[1]+v1[2]+v1[3];
    float s2 = v0[0]*v0[0]+v0[1]*v0[1]+v0[2]*v0[2]+v0[3]*v0[3]
             + v1[0]*v1[0]+v1[1]*v1[1]+v1[2]*v1[2]+v1[3]*v1[3];
    #pragma unroll
    for (int off = 32; off >= 1; off >>= 1) {
        s  += __shfl_xor(s,  off);
        s2 += __shfl_xor(s2, off);
    }
    const float mu = s * (1.f / 384.f);
    const float rs = rsqrtf(s2 * (1.f / 384.f) - mu * mu + 1e-5f);
    unsigned short* dst = xn + (size_t)p * 384;
    f32x4 g0 = *(const f32x4*)(gamma + l * 4);
    f32x4 b0 = *(const f32x4*)(beta  + l * 4);
    u16x4 o0;
    #pragma unroll
    for (int j = 0; j < 4; ++j) o0[j] = f2bf((v0[j] - mu) * rs * g0[j] + b0[j]);
    *(u16x4*)(dst + l * 4) = o0;
    if (l < 32) {
        f32x4 g1 = *(const f32x4*)(gamma + 256 + l * 4);
        f32x4 b1 = *(const f32x4*)(beta  + 256 + l * 4);
        u16x4 o1;
        #pragma unroll
        for (int j = 0; j < 4; ++j) o1[j] = f2bf((v1[j] - mu) * rs * g1[j] + b1[j]);
        *(u16x4*)(dst + 256 + l * 4) = o1;
    }
    // zero dead parities (0,1,1)@+12480 and (1,1,0)@+798720 : 48 f32x4 each (NT)
    if (l < 48) {
        const int ob = ob_of_p(p);
        const f32x4 z = {0.f, 0.f, 0.f, 0.f};
        __builtin_nontemporal_store(z, (f32x4*)(outf + ob + 12480  + l * 4));
        __builtin_nontemporal_store(z, (f32x4*)(outf + ob + 798720 + l * 4));
    }
}

// kernel 2: MFMA GEMM + scatter epilogue. 2-phase dbuf + COUNTED vmcnt (T4).
// 128x128 tile, BK=64, 256 thr (4 waves 2x2). A+B staged via global_load_lds
// into 32 KB buffers, double-buffered (64 KB). Per K-step:
//   issue stage(t+1) -> s_waitcnt vmcnt(8)+s_barrier (tile t ready, t+1 flying)
//   -> compute(t) -> s_waitcnt lgkmcnt(0)+s_barrier (buf[cur] free).
// All waits fused into single asm-with-barrier blocks (memory clobber) so the
// compiler cannot move LDS/VMEM ops across them. NT output stores.
__global__ __launch_bounds__(256) void gemm7_kernel(const unsigned short* __restrict__ xn,
                                                    const unsigned short* __restrict__ wt,
                                                    float* __restrict__ outf) {
    __shared__ char lds[65536];   // buf k at k*32768: A [0,16K), B [16K,32K)
    const char* xb = (const char*)xn;
    const char* wb = (const char*)wt;
    const int tid = threadIdx.x;
    const int wv = tid >> 6, l = tid & 63;
    int bid = blockIdx.x;
    bid = (bid & 7) * 288 + (bid >> 3);  // XCD swizzle (2304 = 8*288, bijective)
    const int mt = bid / 9, nt = bid % 9;
    const int m0 = mt * 128, n0 = nt * 128;
    const int wm = wv >> 1, wn = wv & 1;

    // staging: inst i covers rows wv*32+i*8..+8; lane l -> row +(l>>3), chunk l&7
    // LDS dest linear; global source pre-swizzled (chunk ^ row&7)
    size_t srcA[4], srcB[4];
    int ldsA[4], ldsB[4];
    #pragma unroll
    for (int i = 0; i < 4; ++i) {
        const int r = wv * 32 + i * 8 + (l >> 3);
        const int swz = ((l & 7) * 16) ^ ((r & 7) << 4);
        srcA[i] = (size_t)(m0 + r) * 768 + swz;
        srcB[i] = (size_t)(n0 + r) * 768 + swz;
        ldsA[i] = (wv * 32 + i * 8) * 128;
        ldsB[i] = 16384 + (wv * 32 + i * 8) * 128;
    }

    f32x4 acc[4][4];
    const f32x4 fz = {0.f, 0.f, 0.f, 0.f};
    #pragma unroll
    for (int m = 0; m < 4; ++m)
        #pragma unroll
        for (int n = 0; n < 4; ++n) acc[m][n] = fz;

    int arow[4], brow[4];
    #pragma unroll
    for (int i = 0; i < 4; ++i) {
        arow[i] = wm * 64 + i * 16 + (l & 15);
        brow[i] = wn * 64 + i * 16 + (l & 15);
    }
    const int kbyte0 = (l >> 4) * 16;

    // prologue: stage K-tile 0 into buf 0 (8 loads/thread in flight)
    #pragma unroll
    for (int i = 0; i < 4; ++i) {
        __builtin_amdgcn_global_load_lds((gvoid_t*)(xb + srcA[i]),
                                         (lvoid_t*)(lds + ldsA[i]), 16, 0, 0);
        __builtin_amdgcn_global_load_lds((gvoid_t*)(wb + srcB[i]),
                                         (lvoid_t*)(lds + ldsB[i]), 16, 0, 0);
    }

    #pragma unroll
    for (int t = 0; t < 6; ++t) {        // K = 384 = 6 * 64
        const int cur = (t & 1) * 32768;
        const int nxt = 32768 - cur;
        if (t < 5) {                     // issue stage(t+1): +8 loads (16 in flight)
            #pragma unroll
            for (int i = 0; i < 4; ++i) {
                __builtin_amdgcn_global_load_lds((gvoid_t*)(xb + srcA[i] + (t + 1) * 128),
                                                 (lvoid_t*)(lds + nxt + ldsA[i]), 16, 0, 0);
                __builtin_amdgcn_global_load_lds((gvoid_t*)(wb + srcB[i] + (t + 1) * 128),
                                                 (lvoid_t*)(lds + nxt + ldsB[i]), 16, 0, 0);
            }
            // wait tile t's 8 oldest loads only; tile t+1 stays in flight
            asm volatile("s_waitcnt vmcnt(8)\n\ts_barrier" ::: "memory");
        } else {
            asm volatile("s_waitcnt vmcnt(0)\n\ts_barrier" ::: "memory");
        }
        #pragma unroll
        for (int kk = 0; kk < 2; ++kk) {
            const int kbyte = kbyte0 + kk * 64;
            s16x8 a[4], b[4];
            #pragma unroll
            for (int m = 0; m < 4; ++m)
                a[m] = *(const s16x8*)(lds + cur + arow[m] * 128 + (kbyte ^ ((arow[m] & 7) << 4)));
            #pragma unroll
            for (int n = 0; n < 4; ++n)
                b[n] = *(const s16x8*)(lds + cur + 16384 + brow[n] * 128 + (kbyte ^ ((brow[n] & 7) << 4)));
            #pragma unroll
            for (int m = 0; m < 4; ++m)
                #pragma unroll
                for (int n = 0; n < 4; ++n)
                    acc[m][n] = __builtin_amdgcn_mfma_f32_16x16x32_bf16(a[m], b[n], acc[m][n], 0, 0, 0);
        }
        // all ds_reads of buf[cur] complete before any wave restages into it
        asm volatile("s_waitcnt lgkmcnt(0)\n\ts_barrier" ::: "memory");
    }

    // epilogue: D row = (l>>4)*4 + reg, col = l&15 (per 16x16 fragment); NT stores
    int coladd[4];
    #pragma unroll
    for (int n = 0; n < 4; ++n) {
        const int gnb = n0 + wn * 64 + n * 16;   // 16-col group never crosses a slot
        const int s = gnb / 192;
        int d;
        if      (s == 0) d = 0;        // ch0 -> (0,0,0)
        else if (s == 1) d = 786432;   // ch1 -> (1,0,0)
        else if (s == 2) d = 786624;   // ch4 -> (1,0,1)
        else if (s == 3) d = 12288;    // ch5 -> (0,1,0)
        else if (s == 4) d = 192;      // ch6 -> (0,0,1)
        else             d = 798912;   // ch7 -> (1,1,1)
        coladd[n] = d + (gnb % 192) + (l & 15);
    }
    const int pb = m0 + wm * 64 + (l >> 4) * 4;
    #pragma unroll
    for (int m = 0; m < 4; ++m) {
        #pragma unroll
        for (int r = 0; r < 4; ++r) {
            const int ob = ob_of_p(pb + m * 16 + r);
            #pragma unroll
            for (int n = 0; n < 4; ++n)
                __builtin_nontemporal_store(acc[m][n][r], outf + ob + coladd[n]);
        }
    }
}

// ============================ FALLBACK (round-1) PATH ========================

__global__ __launch_bounds__(256) void ln_kernel(const float* __restrict__ x,
                                                 const float* __restrict__ gamma,
                                                 const float* __restrict__ beta,
                                                 float* __restrict__ outf) {
    const int wv = threadIdx.x >> 6;
    const int l  = threadIdx.x & 63;
    const int p  = blockIdx.x * 4 + wv;
    const float* row = x + (size_t)p * 384;
    f32x4 v0 = *(const f32x4*)(row + l * 4);
    f32x4 v1 = {0.f, 0.f, 0.f, 0.f};
    if (l < 32) v1 = *(const f32x4*)(row + 256 + l * 4);
    float s  = v0[0]+v0[1]+v0[2]+v0[3] + v1[0]+v1[1]+v1[2]+v1[3];
    float s2 = v0[0]*v0[0]+v0[1]*v0[1]+v0[2]*v0[2]+v0[3]*v0[3]
             + v1[0]*v1[0]+v1[1]*v1[1]+v1[2]*v1[2]+v1[3]*v1[3];
    #pragma unroll
    for (int off = 32; off >= 1; off >>= 1) {
        s  += __shfl_xor(s,  off);
        s2 += __shfl_xor(s2, off);
    }
    const float mu = s * (1.f / 384.f);
    const float rs = rsqrtf(s2 * (1.f / 384.f) - mu * mu + 1e-5f);
    unsigned short* dst = (unsigned short*)(outf + ob_of_p(p) + 12480);
    f32x4 g0 = *(const f32x4*)(gamma + l * 4);
    f32x4 b0 = *(const f32x4*)(beta  + l * 4);
    u16x4 o0;
    #pragma unroll
    for (int j = 0; j < 4; ++j) o0[j] = f2bf((v0[j] - mu) * rs * g0[j] + b0[j]);
    *(u16x4*)(dst + l * 4) = o0;
    if (l < 32) {
        f32x4 g1 = *(const f32x4*)(gamma + 256 + l * 4);
        f32x4 b1 = *(const f32x4*)(beta  + 256 + l * 4);
        u16x4 o1;
        #pragma unroll
        for (int j = 0; j < 4; ++j) o1[j] = f2bf((v1[j] - mu) * rs * g1[j] + b1[j]);
        *(u16x4*)(dst + 256 + l * 4) = o1;
    }
}

__global__ __launch_bounds__(256) void wt_kernel(const float* __restrict__ W,
                                                 float* __restrict__ outf) {
    const int t = blockIdx.x * 256 + threadIdx.x;
    const int k = t % 384;
    const int n = t / 384;
    const int s = n / 192;
    const int oc = (s < 2 ? s : s + 2) * 192 + (n % 192);
    const float v = W[(size_t)k * 1536 + oc];
    unsigned short* dst = (unsigned short*)(outf + ob_of_p(n) + 798720);
    dst[k] = f2bf(v);
}

__global__ __launch_bounds__(256) void gemm_kernel(float* __restrict__ outf) {
    __shared__ char lds[32768];
    const char* gbase = (const char*)outf;
    const int tid = threadIdx.x;
    const int wv = tid >> 6, l = tid & 63;
    int bid = blockIdx.x;
    bid = (bid & 7) * 288 + (bid >> 3);
    const int mt = bid / 9, nt = bid % 9;
    const int m0 = mt * 128, n0 = nt * 128;
    size_t srcA[4], srcB[4];
    int ldsA[4], ldsB[4];
    #pragma unroll
    for (int i = 0; i < 4; ++i) {
        const int r = wv * 32 + i * 8 + (l >> 3);
        const int swz = ((l & 7) * 16) ^ ((r & 7) << 4);
        srcA[i] = (size_t)(ob_of_p(m0 + r) + 12480)  * 4 + swz;
        srcB[i] = (size_t)(ob_of_p(n0 + r) + 798720) * 4 + swz;
        ldsA[i] = (wv * 32 + i * 8) * 128;
        ldsB[i] = 16384 + (wv * 32 + i * 8) * 128;
    }
    f32x4 acc[4][4];
    const f32x4 fz = {0.f, 0.f, 0.f, 0.f};
    #pragma unroll
    for (int m = 0; m < 4; ++m)
        #pragma unroll
        for (int n = 0; n < 4; ++n) acc[m][n] = fz;
    const int wm = wv >> 1, wn = wv & 1;
    int arow[4], brow[4];
    #pragma unroll
    for (int i = 0; i < 4; ++i) {
        arow[i] = wm * 64 + i * 16 + (l & 15);
        brow[i] = wn * 64 + i * 16 + (l & 15);
    }
    const int kbyte0 = (l >> 4) * 16;
    for (int t = 0; t < 6; ++t) {
        const int kb = t * 128;
        #pragma unroll
        for (int i = 0; i < 4; ++i)
            __builtin_amdgcn_global_load_lds((gvoid_t*)(gbase + srcA[i] + kb),
                                             (lvoid_t*)(lds + ldsA[i]), 16, 0, 0);
        #pragma unroll
        for (int i = 0; i < 4; ++i)
            __builtin_amdgcn_global_load_lds((gvoid_t*)(gbase + srcB[i] + kb),
                                             (lvoid_t*)(lds + ldsB[i]), 16, 0, 0);
        __syncthreads();
        #pragma unroll
        for (int kk = 0; kk < 2; ++kk) {
            const int kbyte = kbyte0 + kk * 64;
            s16x8 a[4], b[4];
            #pragma unroll
            for (int m = 0; m < 4; ++m)
                a[m] = *(const s16x8*)(lds + arow[m] * 128 + (kbyte ^ ((arow[m] & 7) << 4)));
            #pragma unroll
            for (int n = 0; n < 4; ++n)
                b[n] = *(const s16x8*)(lds + 16384 + brow[n] * 128 + (kbyte ^ ((brow[n] & 7) << 4)));
            #pragma unroll
            for (int m = 0; m < 4; ++m)
                #pragma unroll
                for (int n = 0; n < 4; ++n)
                    acc[m][n] = __builtin_amdgcn_mfma_f32_16x16x32_bf16(a[m], b[n], acc[m][n], 0, 0, 0);
        }
        __syncthreads();
    }
    int coladd[4];
    #pragma unroll
    for (int n = 0; n < 4; ++n) {
        const int gnb = n0 + wn * 64 + n * 16;
        const int s = gnb / 192;
        int d;
        if      (s == 0) d = 0;
        else if (s == 1) d = 786432;
        else if (s == 2) d = 786624;
        else if (s == 3) d = 12288;
        else if (s == 4) d = 192;
        else             d = 798912;
        coladd[n] = d + (gnb % 192) + (l & 15);
    }
    const int pb = m0 + wm * 64 + (l >> 4) * 4;
    #pragma unroll
    for (int m = 0; m < 4; ++m) {
        #pragma unroll
        for (int r = 0; r < 4; ++r) {
            const int ob = ob_of_p(pb + m * 16 + r);
            #pragma unroll
            for (int n = 0; n < 4; ++n)
                outf[ob + coladd[n]] = acc[m][n][r];
        }
    }
}

__global__ __launch_bounds__(256) void zero_kernel(float* __restrict__ outf) {
    const int idx = blockIdx.x * 256 + threadIdx.x;
    const int f4 = idx % 48;
    const int pr = (idx / 48) & 1;
    const int p  = idx / 96;
    const f32x4 z = {0.f, 0.f, 0.f, 0.f};
    *(f32x4*)(outf + ob_of_p(p) + (pr ? 798720 : 12480) + f4 * 4) = z;
}

// =============================================================================

extern "C" void kernel_launch(void* const* d_in, const int* in_sizes, int n_in,
                              void* d_out, int out_size, void* d_ws, size_t ws_size,
                              hipStream_t stream) {
    const float* x     = (const float*)d_in[0];
    const float* W     = (const float*)d_in[1];
    const float* gamma = (const float*)d_in[2];
    const float* beta  = (const float*)d_in[3];
    float* out = (float*)d_out;
    const size_t need = 25165824 + 884736;   // xn + Wt bf16
    if (ws_size >= need) {
        unsigned short* xn = (unsigned short*)d_ws;
        unsigned short* wt = (unsigned short*)((char*)d_ws + 25165824);
        lnwt_kernel <<<9920, 256, 0, stream>>>(x, gamma, beta, W, out, xn, wt);
        gemm7_kernel<<<2304, 256, 0, stream>>>(xn, wt, out);
    } else {
        ln_kernel  <<<8192,  256, 0, stream>>>(x, gamma, beta, out);
        wt_kernel  <<<1728,  256, 0, stream>>>(W, out);
        gemm_kernel<<<2304,  256, 0, stream>>>(out);
        zero_kernel<<<12288, 256, 0, stream>>>(out);
    }
}